// Round 25
// baseline (82.897 us; speedup 1.0000x reference)
//
#include <hip/hip_runtime.h>

#define N_      32
#define CIN     128
#define HW_     56
#define COUT    256
#define HP      58                    // padded spatial
#define SP_     (HW_*HW_)             // 3136
#define M_      (N_*SP_)              // 100352
// xp layout: [n][hp(58)][chunk16(8)][wp(58)][16B]  -> 7424 B per (n,hp) row
#define ROWB    7424
#define CHB     928                   // 58*16: bytes per chunk-plane
#define XP_BYTES (N_*HP*ROWB)         // 13,778,944
#define WP_BYTES (9*COUT*CIN)         // 294,912
#define TAPB    32768                 // bytes per tap in wp ([panel(8)][4KB])
#define NWG     ((M_/256)*(COUT/32))  // 3136 work-groups
#define PERX    (NWG/8)               // 392 per XCD
#define RX_BLKS (N_*HP)               // 1856 repack_x blocks
#define RW_BLKS (WP_BYTES/4/256)      // 288 repack_w blocks

typedef int int4v  __attribute__((ext_vector_type(4)));
typedef int int16v __attribute__((ext_vector_type(16)));

// ---- merged repack: blocks [0,1856) do x, [1856,2144) do w ----
// wp layout (lane-ordered B, BN=32): [tap(9)][panel(8)][kc(4)][lane:lh(2)|co32(32)][16B]
//   co = panel*32 + co32, c = kc*32 + lh*16 + byte
// -> conv's ds_read_b128 at base+kc*1024+lane*16 is contiguous 1KB: zero conflicts.
__global__ __launch_bounds__(256) void repack(const int* __restrict__ x32,
                                              const int* __restrict__ w32,
                                              char* __restrict__ xp,
                                              char* __restrict__ wp) {
    int b = blockIdx.x;
    if (b < RX_BLKS) {
        // x: int32 NCHW -> int8 [n][hp][chunk][wp][16B], halo zero-filled
        __shared__ char s8[CIN * HW_];                // [c][w] 7168 B
        int n = b / HP;
        int hp = b - n * HP;
        int h = hp - 1;                               // source h
        bool live = (h >= 0) && (h < HW_);
        if (live) {
            const int* src = x32 + ((size_t)(n * CIN)) * SP_ + h * HW_;
            for (int i = threadIdx.x; i < CIN * HW_; i += 256) {
                int c = i / HW_, w = i - c * HW_;
                s8[i] = (char)src[c * SP_ + w];
            }
        }
        __syncthreads();
        int* dst = (int*)(xp + (size_t)b * ROWB);
        for (int i = threadIdx.x; i < 8 * 232; i += 256) {   // 1856 dwords per row
            int chunk = i / 232, r = i - chunk * 232;
            int wp_ = r >> 2, sub = r & 3;
            int w = wp_ - 1;
            int v = 0;
            if (live && w >= 0 && w < HW_) {
                int c0 = chunk * 16 + sub * 4;
                int v0 = (unsigned char)s8[(c0 + 0) * HW_ + w];
                int v1 = (unsigned char)s8[(c0 + 1) * HW_ + w];
                int v2 = (unsigned char)s8[(c0 + 2) * HW_ + w];
                int v3 = (unsigned char)s8[(c0 + 3) * HW_ + w];
                v = v0 | (v1 << 8) | (v2 << 16) | (v3 << 24);
            }
            dst[i] = v;
        }
    } else {
        // w: int32 [co][c][kh][kw] -> lane-ordered int8 layout (see header comment)
        int i = (b - RX_BLKS) * 256 + threadIdx.x;    // dword index < 73728
        int tap   = i >> 13;                          // 8192 dwords per tap
        int r     = i & 8191;
        int panel = r >> 10;                          // 1024 dwords per panel
        int r2    = r & 1023;
        int kc    = r2 >> 8;
        int lh    = (r2 >> 7) & 1;
        int co32  = (r2 >> 2) & 31;
        int db    = r2 & 3;                           // dword within 16B
        int co = panel * 32 + co32;
        int c0 = kc * 32 + lh * 16 + db * 4;
        const int* s = w32 + co * (CIN * 9) + c0 * 9 + tap;
        int v0 = s[0]  & 0xff;
        int v1 = s[9]  & 0xff;
        int v2 = s[18] & 0xff;
        int v3 = s[27] & 0xff;
        ((int*)wp)[i] = v0 | (v1 << 8) | (v2 << 16) | (v3 << 24);
    }
}

// -------- main: implicit GEMM, BM=256 BN=32, wave tile 64x32, acc[2][1] --------
// Occupancy unlock: acc=32 AGPR makes ~142 unified regs -> 3 waves/SIMD under
// __launch_bounds__(256,3); LDS = 9 taps x 4KB = 36KB -> 3 blocks/CU.
// Single-barrier 9-tap stage, lane-ordered conflict-free B, A ping-pong depth 1,
// XCD co-fastest swizzle (8 consecutive co-panels share one A window per XCD).
__global__ __launch_bounds__(256, 3) void conv_mfma(const char* __restrict__ xp,
                                                    const char* __restrict__ wp,
                                                    const int*  __restrict__ bias,
                                                    const float* __restrict__ wsc,
                                                    int* __restrict__ out) {
    __shared__ char Bs[9 * 4096];                 // 36864 B
    const int tid  = threadIdx.x;
    const int wave = tid >> 6, lane = tid & 63;
    const int l31 = lane & 31, lh = lane >> 5;

    // XCD swizzle (3136 % 8 == 0, bijective): work id co-fastest
    int bid = blockIdx.x;
    int w_  = (bid & 7) * PERX + (bid >> 3);
    const int co0    = (w_ & 7) << 5;
    const int m_base = (w_ >> 3) << 8;

    const char* aptrT[2];
    int tb[2];
#pragma unroll
    for (int mf = 0; mf < 2; ++mf) {
        tb[mf] = m_base + wave * 64 + mf * 32;    // multiple of 32; 3136%32==0 -> same n
        int row = tb[mf] + l31;
        int n  = row / SP_;
        int sp = row - n * SP_;
        int ho = sp / HW_;
        int wo = sp - ho * HW_;
        aptrT[mf] = xp + (size_t)(n * HP + ho) * ROWB + lh * CHB + wo * 16;
    }

    const char* wpb = wp + (co0 >> 5) * 4096;     // this block's panel base

    int16v acc[2] = {};

    // stage all 9 taps (36 KB); both sides LINEAR (lane-ordered layout)
    for (int i = wave; i < 36; i += 4) {
        int p = (i << 10) + (lane << 4);          // byte offset in staged region
        const char* src = wpb + (p >> 12) * TAPB + (p & 4095);
        __builtin_amdgcn_global_load_lds(
            (const __attribute__((address_space(1))) void*)src,
            (__attribute__((address_space(3))) void*)&Bs[i << 10], 16, 0, 0);
    }

    // load A fragments for one tap into a named register buffer
    auto aload = [&](int4v a[2][4], int tap) {
        int kh = tap / 3, kw = tap - kh * 3;
        int aoff = kh * ROWB + kw * 16;
#pragma unroll
        for (int kc = 0; kc < 4; ++kc) {
            a[0][kc] = *(const int4v*)(aptrT[0] + aoff + kc * (2 * CHB));
            a[1][kc] = *(const int4v*)(aptrT[1] + aoff + kc * (2 * CHB));
        }
    };

    // one tap: 4 contiguous ds_read_b128 + 8 MFMAs on the given A buffer
    auto ctap = [&](const int4v a[2][4], int tap) {
        int bbase = (tap << 12) + (lane << 4);
        __builtin_amdgcn_s_setprio(1);
        int4v b0[4];
#pragma unroll
        for (int kc = 0; kc < 4; ++kc)
            b0[kc] = *(const int4v*)&Bs[bbase + kc * 1024];
#pragma unroll
        for (int kc = 0; kc < 4; ++kc) {
            acc[0] = __builtin_amdgcn_mfma_i32_32x32x32_i8(a[0][kc], b0[kc], acc[0], 0, 0, 0);
            acc[1] = __builtin_amdgcn_mfma_i32_32x32x32_i8(a[1][kc], b0[kc], acc[1], 0, 0, 0);
        }
        __builtin_amdgcn_s_setprio(0);
    };

    int4v aA[2][4], aB[2][4];

    aload(aA, 0);                 // overlap the stage drain
    __syncthreads();              // all 9 slabs ready — the ONLY barrier

    aload(aB, 1); ctap(aA, 0);
    aload(aA, 2); ctap(aB, 1);
    aload(aB, 3); ctap(aA, 2);
    aload(aA, 4); ctap(aB, 3);
    aload(aB, 5); ctap(aA, 4);
    aload(aA, 6); ctap(aB, 5);
    aload(aB, 7); ctap(aA, 6);
    aload(aA, 8); ctap(aB, 7);
    ctap(aA, 8);

    // epilogue: C/D col = l31 = co, row = (r&3)+8*(r>>2)+4*lh = sp offset;
    // 4 consecutive sp -> dwordx4
#pragma unroll
    for (int mf = 0; mf < 2; ++mf) {
        int nu  = tb[mf] / SP_;
        int sp0 = tb[mf] - nu * SP_;
        int co = co0 + l31;
        float s = (0.02f * wsc[co]) / 0.1f;
        int bs = bias[co];
        int* ob = out + ((size_t)(nu * COUT + co)) * SP_ + sp0 + (lh << 2);
#pragma unroll
        for (int g = 0; g < 4; ++g) {
            int4v qv;
#pragma unroll
            for (int r = 0; r < 4; ++r) {
                float v = (float)(acc[mf][g * 4 + r] + bs) * s;
                int q = (int)rintf(v);
                qv[r] = q < -128 ? -128 : (q > 127 ? 127 : q);
            }
            *(int4v*)(ob + g * 8) = qv;
        }
    }
}

extern "C" void kernel_launch(void* const* d_in, const int* in_sizes, int n_in,
                              void* d_out, int out_size, void* d_ws, size_t ws_size,
                              hipStream_t stream) {
    const int*   x32  = (const int*)d_in[0];
    const int*   w32  = (const int*)d_in[1];
    const int*   bias = (const int*)d_in[2];
    const float* wsc  = (const float*)d_in[3];

    char* xp = (char*)d_ws;
    char* wp = xp + XP_BYTES;

    repack<<<dim3(RX_BLKS + RW_BLKS), 256, 0, stream>>>(x32, w32, xp, wp);
    conv_mfma<<<dim3(NWG), 256, 0, stream>>>(xp, wp, bias, wsc, (int*)d_out);
}

// Round 30
// 65.756 us; speedup vs baseline: 1.2607x; 1.2607x over previous
//
#include <hip/hip_runtime.h>

#define N_      32
#define CIN     128
#define HW_     56
#define COUT    256
#define HP      58                    // padded spatial
#define SP_     (HW_*HW_)             // 3136
#define M_      (N_*SP_)              // 100352
// xp layout: [n][hp(58)][chunk16(8)][wp(58)][16B]  -> 7424 B per (n,hp) row
#define ROWB    7424
#define CHB     928                   // 58*16: bytes per chunk-plane
#define XP_BYTES (N_*HP*ROWB)         // 13,778,944
#define WP_BYTES (9*COUT*CIN)         // 294,912
#define TAPB    (COUT*CIN)            // 32768: bytes per tap in wp
#define NWG     ((M_/256)*(COUT/64))  // 1568 work-groups
#define PERX    (NWG/8)               // 196 per XCD
#define RX_BLKS (N_*HP)               // 1856 repack_x blocks
#define RW_BLKS (WP_BYTES/4/256)      // 288 repack_w blocks

typedef int int4v  __attribute__((ext_vector_type(4)));
typedef int int16v __attribute__((ext_vector_type(16)));

// ---- merged repack: blocks [0,1856) do x, [1856,2144) do w ----
__global__ __launch_bounds__(256) void repack(const int* __restrict__ x32,
                                              const int* __restrict__ w32,
                                              char* __restrict__ xp,
                                              char* __restrict__ wp) {
    int b = blockIdx.x;
    if (b < RX_BLKS) {
        // x: int32 NCHW -> int8 [n][hp][chunk][wp][16B], halo zero-filled
        __shared__ char s8[CIN * HW_];                // [c][w] 7168 B
        int n = b / HP;
        int hp = b - n * HP;
        int h = hp - 1;                               // source h
        bool live = (h >= 0) && (h < HW_);
        if (live) {
            const int* src = x32 + ((size_t)(n * CIN)) * SP_ + h * HW_;
            for (int i = threadIdx.x; i < CIN * HW_; i += 256) {
                int c = i / HW_, w = i - c * HW_;
                s8[i] = (char)src[c * SP_ + w];
            }
        }
        __syncthreads();
        int* dst = (int*)(xp + (size_t)b * ROWB);
        for (int i = threadIdx.x; i < 8 * 232; i += 256) {   // 1856 dwords per row
            int chunk = i / 232, r = i - chunk * 232;
            int wp_ = r >> 2, sub = r & 3;
            int w = wp_ - 1;
            int v = 0;
            if (live && w >= 0 && w < HW_) {
                int c0 = chunk * 16 + sub * 4;
                int v0 = (unsigned char)s8[(c0 + 0) * HW_ + w];
                int v1 = (unsigned char)s8[(c0 + 1) * HW_ + w];
                int v2 = (unsigned char)s8[(c0 + 2) * HW_ + w];
                int v3 = (unsigned char)s8[(c0 + 3) * HW_ + w];
                v = v0 | (v1 << 8) | (v2 << 16) | (v3 << 24);
            }
            dst[i] = v;
        }
    } else {
        // w: int32 [co][c][kh][kw] -> int8 [tap][co][c]
        int i = (b - RX_BLKS) * 256 + threadIdx.x;    // dword index < 73728
        int tap = i >> 13;
        int r   = i & 8191;
        int co  = r >> 5;
        int c4  = r & 31;
        const int* s = w32 + (co * CIN + c4 * 4) * 9 + tap;
        int v0 = s[0]  & 0xff;
        int v1 = s[9]  & 0xff;
        int v2 = s[18] & 0xff;
        int v3 = s[27] & 0xff;
        ((int*)wp)[i] = v0 | (v1 << 8) | (v2 << 16) | (v3 << 24);
    }
}

// -------- main: implicit GEMM, BM=256 BN=64, wave tile 64x64, acc[2][2] --------
// Locked-in best (round 18): 9 taps staged once (72 KB, ONE barrier), (256,2),
// A prefetch depth 2 (aA/aB/aC rotation), XCD co-fastest swizzle, dwordx4 epilogue.
__global__ __launch_bounds__(256, 2) void conv_mfma(const char* __restrict__ xp,
                                                    const char* __restrict__ wp,
                                                    const int*  __restrict__ bias,
                                                    const float* __restrict__ wsc,
                                                    int* __restrict__ out) {
    __shared__ char Bs[9 * 8192];                 // 73728 B
    const int tid  = threadIdx.x;
    const int wave = tid >> 6, lane = tid & 63;
    const int l31 = lane & 31, lh = lane >> 5;

    // XCD swizzle (1568 % 8 == 0, bijective): work id co-fastest
    int bid = blockIdx.x;
    int w_  = (bid & 7) * PERX + (bid >> 3);
    const int co0    = (w_ & 3) << 6;
    const int m_base = (w_ >> 2) << 8;

    const char* aptrT[2];
    int tb[2];
#pragma unroll
    for (int mf = 0; mf < 2; ++mf) {
        tb[mf] = m_base + wave * 64 + mf * 32;    // multiple of 32; 3136%32==0 -> same n
        int row = tb[mf] + l31;
        int n  = row / SP_;
        int sp = row - n * SP_;
        int ho = sp / HW_;
        int wo = sp - ho * HW_;
        aptrT[mf] = xp + (size_t)(n * HP + ho) * ROWB + lh * CHB + wo * 16;
    }

    const char* wpb = wp + co0 * CIN;             // this block's 64-co panel

    int16v acc[2][2] = {};

    // stage all 9 taps (72 KB); linear dest, inverse-swizzled source (involution)
    for (int i = wave; i < 72; i += 4) {
        int p = (i << 10) + (lane << 4);          // byte offset in staged region
        int q = (p & 8191) ^ (((p >> 7) & 7) << 4);
        const char* src = wpb + (p >> 13) * TAPB + q;
        __builtin_amdgcn_global_load_lds(
            (const __attribute__((address_space(1))) void*)src,
            (__attribute__((address_space(3))) void*)&Bs[i << 10], 16, 0, 0);
    }

    // load A fragments for one tap into a named register buffer
    auto aload = [&](int4v a[2][4], int tap) {
        int kh = tap / 3, kw = tap - kh * 3;
        int aoff = kh * ROWB + kw * 16;
#pragma unroll
        for (int kc = 0; kc < 4; ++kc) {
            a[0][kc] = *(const int4v*)(aptrT[0] + aoff + kc * (2 * CHB));
            a[1][kc] = *(const int4v*)(aptrT[1] + aoff + kc * (2 * CHB));
        }
    };

    const int sw = (l31 & 7) << 4;

    // one tap: 8 ds_read_b128 + 16 MFMAs on the given A buffer
    auto ctap = [&](const int4v a[2][4], int tap) {
        int bbase = tap << 13;
        __builtin_amdgcn_s_setprio(1);
        int4v b0[4], b1[4];
#pragma unroll
        for (int kc = 0; kc < 4; ++kc) {
            int koff = bbase + kc * 32 + (lh << 4);
            b0[kc] = *(const int4v*)&Bs[(koff + (l31 << 7)) ^ sw];
            b1[kc] = *(const int4v*)&Bs[(koff + ((l31 + 32) << 7)) ^ sw];
        }
#pragma unroll
        for (int kc = 0; kc < 4; ++kc) {
            acc[0][0] = __builtin_amdgcn_mfma_i32_32x32x32_i8(a[0][kc], b0[kc], acc[0][0], 0, 0, 0);
            acc[1][0] = __builtin_amdgcn_mfma_i32_32x32x32_i8(a[1][kc], b0[kc], acc[1][0], 0, 0, 0);
            acc[0][1] = __builtin_amdgcn_mfma_i32_32x32x32_i8(a[0][kc], b1[kc], acc[0][1], 0, 0, 0);
            acc[1][1] = __builtin_amdgcn_mfma_i32_32x32x32_i8(a[1][kc], b1[kc], acc[1][1], 0, 0, 0);
        }
        __builtin_amdgcn_s_setprio(0);
    };

    int4v aA[2][4], aB[2][4], aC[2][4];

    aload(aA, 0);                 // overlap the stage drain
    aload(aB, 1);
    __syncthreads();              // all 9 slabs ready — the ONLY barrier

    aload(aC, 2); ctap(aA, 0);
    aload(aA, 3); ctap(aB, 1);
    aload(aB, 4); ctap(aC, 2);
    aload(aC, 5); ctap(aA, 3);
    aload(aA, 6); ctap(aB, 4);
    aload(aB, 7); ctap(aC, 5);
    aload(aC, 8); ctap(aA, 6);
    ctap(aB, 7);
    ctap(aC, 8);

    // epilogue: C/D row = (r&3) + 8*(r>>2) + 4*lh; 4 consecutive sp -> dwordx4
#pragma unroll
    for (int mf = 0; mf < 2; ++mf) {
        int nu  = tb[mf] / SP_;
        int sp0 = tb[mf] - nu * SP_;
#pragma unroll
        for (int nf = 0; nf < 2; ++nf) {
            int co = co0 + nf * 32 + l31;
            float s = (0.02f * wsc[co]) / 0.1f;
            int bs = bias[co];
            int* ob = out + ((size_t)(nu * COUT + co)) * SP_ + sp0 + (lh << 2);
#pragma unroll
            for (int g = 0; g < 4; ++g) {
                int4v qv;
#pragma unroll
                for (int r = 0; r < 4; ++r) {
                    float v = (float)(acc[mf][nf][g * 4 + r] + bs) * s;
                    int q = (int)rintf(v);
                    qv[r] = q < -128 ? -128 : (q > 127 ? 127 : q);
                }
                *(int4v*)(ob + g * 8) = qv;
            }
        }
    }
}

extern "C" void kernel_launch(void* const* d_in, const int* in_sizes, int n_in,
                              void* d_out, int out_size, void* d_ws, size_t ws_size,
                              hipStream_t stream) {
    const int*   x32  = (const int*)d_in[0];
    const int*   w32  = (const int*)d_in[1];
    const int*   bias = (const int*)d_in[2];
    const float* wsc  = (const float*)d_in[3];

    char* xp = (char*)d_ws;
    char* wp = xp + XP_BYTES;

    repack<<<dim3(RX_BLKS + RW_BLKS), 256, 0, stream>>>(x32, w32, xp, wp);
    conv_mfma<<<dim3(NWG), 256, 0, stream>>>(xp, wp, bias, wsc, (int*)d_out);
}